// Round 18
// baseline (129.623 us; speedup 1.0000x reference)
//
#include <hip/hip_runtime.h>
#include <math.h>

#define B_ 64
#define IC 2048
#define OC 32
#define OD 16
#define ID 8

typedef __attribute__((ext_vector_type(8)))  short s16x8;
typedef __attribute__((ext_vector_type(16))) float f32x16;

#define GLOAD_LDS16(gp, lp)                                                       \
  __builtin_amdgcn_global_load_lds((const __attribute__((address_space(1))) void*)(gp), \
                                   (__attribute__((address_space(3))) void*)(lp), \
                                   16, 0, 0)

__device__ __forceinline__ unsigned short f2bf(float f) {      // RNE f32->bf16
  unsigned u = __float_as_uint(f);
  return (unsigned short)((u + 0x7fffu + ((u >> 16) & 1u)) >> 16);
}
__device__ __forceinline__ float bf2f(unsigned short h) {
  return __uint_as_float(((unsigned)h) << 16);
}
__device__ __forceinline__ f32x16 mfma16(s16x8 a, s16x8 b, f32x16 c) {
  return __builtin_amdgcn_mfma_f32_32x32x16_bf16(a, b, c, 0, 0, 0);
}
__device__ __forceinline__ float dot8(const float4 w0, const float4 w1,
                                      const float4 xa, const float4 xb) {
  return w0.x*xa.x + w0.y*xa.y + w0.z*xa.z + w0.w*xa.w
       + w1.x*xb.x + w1.y*xb.y + w1.z*xb.z + w1.w*xb.w;
}

// ---------------------------------------------------------------------------
// One-time split-bf16 conversions (proven R14-R16; coalesced both sides).
// Wbf: [i][half][o][d][m] ushort; xb: [i][half][b][m] ushort.
// ---------------------------------------------------------------------------
__global__ __launch_bounds__(256) void convW(const float* __restrict__ W,
                                             unsigned short* __restrict__ Wbf) {
  const int e4 = blockIdx.x * 256 + threadIdx.x;
  const float4 v = ((const float4*)W)[e4];
  const int i = e4 >> 10;
  const int r = (e4 & 1023) << 2;
  ushort4 h, l;
  h.x = f2bf(v.x); l.x = f2bf(v.x - bf2f(h.x));
  h.y = f2bf(v.y); l.y = f2bf(v.y - bf2f(h.y));
  h.z = f2bf(v.z); l.z = f2bf(v.z - bf2f(h.z));
  h.w = f2bf(v.w); l.w = f2bf(v.w - bf2f(h.w));
  *(ushort4*)&Wbf[(size_t)i * 8192 + r]        = h;
  *(ushort4*)&Wbf[(size_t)i * 8192 + 4096 + r] = l;
}

__global__ __launch_bounds__(256) void convX(const float* __restrict__ x,
                                             unsigned short* __restrict__ xb) {
  const int idx = blockIdx.x * 256 + threadIdx.x;
  const int m2 = idx & 1, i = (idx >> 1) & 2047, b = idx >> 12;
  const float4 v = *(const float4*)(x + (size_t)b * 16384 + i * 8 + m2 * 4);
  ushort4 h, l;
  h.x = f2bf(v.x); l.x = f2bf(v.x - bf2f(h.x));
  h.y = f2bf(v.y); l.y = f2bf(v.y - bf2f(h.y));
  h.z = f2bf(v.z); l.z = f2bf(v.z - bf2f(h.z));
  h.w = f2bf(v.w); l.w = f2bf(v.w - bf2f(h.w));
  *(ushort4*)&xb[(size_t)i * 1024 + b * 8 + m2 * 4]       = h;
  *(ushort4*)&xb[(size_t)i * 1024 + 512 + b * 8 + m2 * 4] = l;
}

// ---------------------------------------------------------------------------
// R18 MFMA routing pass = R16 structure (no LDS, no barriers, scrambled vs,
// depth-2 register prefetch), run at NCH=256 (CI=8, grid 2048 = 8 blocks/CU)
// for 1.5-2x the resident waves — the R17 budget showed fusedM at ~20us vs a
// ~7us floor with only 4 waves/SIMD to hide L2/L3 latency; this is the TLP
// A/B. Per-XCD Wbf working set stays exactly L2-sized (32 ch x 128KB = 4MB);
// same-ch blocks stay on one XCD (bid+256 = +0 mod 8).
// ---------------------------------------------------------------------------
template<bool WEIGHTED, int NCH>
__global__ __launch_bounds__(256) void fusedM(
    const unsigned short* __restrict__ Wbf, const unsigned short* __restrict__ xb,
    const float* __restrict__ vss, float* __restrict__ part,
    float* __restrict__ zpart)
{
  constexpr int CI = IC / NCH;
  const int t     = threadIdx.x;
  const int ch    = blockIdx.x % NCH;
  const int q     = blockIdx.x / NCH;
  const int lane  = t & 63;
  const int wv    = t >> 6;
  const int s     = q * 4 + wv;          // 0..31
  const int opair = s >> 1;
  const int bt    = s & 1;
  const int l31   = lane & 31;
  const int hb    = lane >> 5;
  const int i0    = ch * CI;

  const unsigned short* ap =
      Wbf + (size_t)i0 * 8192 + opair * 256 + (l31 >> 4) * 128 + (lane & 15) * 8;
  const unsigned short* bp =
      xb + (size_t)i0 * 1024 + hb * 512 + bt * 256 + l31 * 8;

  f32x16 acc = (f32x16)0.0f;
  float zA = 0.f, zB = 0.f;
  float vsr[16];

  if constexpr (WEIGHTED) {
    const float* vp = vss + s * 1024 + hb * 32 + l31;   // coalesced 256B/ld
#pragma unroll
    for (int r = 0; r < 16; ++r) vsr[r] = vp[r * 64];
  }

  s16x8 AH[3], AL[3], BV[3];
  AH[0] = *(const s16x8*)ap;
  AL[0] = *(const s16x8*)(ap + 4096);
  BV[0] = *(const s16x8*)bp;
  if (CI > 1) {
    AH[1] = *(const s16x8*)(ap + 8192);
    AL[1] = *(const s16x8*)(ap + 8192 + 4096);
    BV[1] = *(const s16x8*)(bp + 1024);
  }

#pragma unroll
  for (int ii = 0; ii < CI; ++ii) {
    const int cs = ii % 3;
    const int ns = (ii + 2) % 3;
    if (ii + 2 < CI) {                       // issue 2 iters ahead
      AH[ns] = *(const s16x8*)(ap + (size_t)(ii + 2) * 8192);
      AL[ns] = *(const s16x8*)(ap + (size_t)(ii + 2) * 8192 + 4096);
      BV[ns] = *(const s16x8*)(bp + (size_t)(ii + 2) * 1024);
    }

    if constexpr (!WEIGHTED) {
      acc = mfma16(AH[cs], BV[cs], acc);
      acc = mfma16(AL[cs], BV[cs], acc);
    } else {
      f32x16 u = mfma16(AH[cs], BV[cs], (f32x16)0.0f);
      u = mfma16(AL[cs], BV[cs], u);
      float pdA = 0.f, pdB = 0.f;
#pragma unroll
      for (int r = 0; r < 8; ++r)  pdA = fmaf(u[r], vsr[r], pdA);
#pragma unroll
      for (int r = 8; r < 16; ++r) pdB = fmaf(u[r], vsr[r], pdB);
      pdA += __shfl_xor(pdA, 32);            // add other hb's 8 d's
      pdB += __shfl_xor(pdB, 32);
      const float pA = __expf(pdA), pB = __expf(pdB);
#pragma unroll
      for (int r = 0; r < 8; ++r)  acc[r] = fmaf(pA, u[r], acc[r]);
#pragma unroll
      for (int r = 8; r < 16; ++r) acc[r] = fmaf(pB, u[r], acc[r]);
      zA += pA; zB += pB;
    }
  }

  // scrambled, coalesced epilogue
  float* op = part + (size_t)ch * 32768;
#pragma unroll
  for (int r = 0; r < 16; ++r)
    op[(s * 16 + r) * 64 + hb * 32 + l31] = acc[r];
  if constexpr (WEIGHTED) {
    if (lane < 32) {
      zpart[(size_t)ch * 2048 + (s * 2 + 0) * 32 + lane] = zA;
      zpart[(size_t)ch * 2048 + (s * 2 + 1) * 32 + lane] = zB;
    }
  }
}

// ---------------------------------------------------------------------------
// Reduce+squash over scrambled part; vss kept scrambled (coalesced both
// directions); PASS 2 writes standard-layout out. grid 64 x 512.
// ---------------------------------------------------------------------------
template<int PASS, int NCH>
__global__ __launch_bounds__(512) void rsqM(
    const float* __restrict__ part, const float* __restrict__ zpart,
    float* __restrict__ vss, float* __restrict__ out)
{
  __shared__ float rzs[32];
  __shared__ float sqs[512];
  const int t   = threadIdx.x;
  const int blk = blockIdx.x;
  const int s   = blk >> 1, oo = blk & 1;
  const int l31 = t & 31, hb = (t >> 5) & 1, rr = t >> 6;
  const size_t tid = (size_t)blk * 512 + t;

  float acc = 0.f;
#pragma unroll 8
  for (int ch = 0; ch < NCH; ++ch) acc += part[(size_t)ch * 32768 + tid];

  if constexpr (PASS == 0) {
    if (t < 32) rzs[t] = 1.f / 2048.f;
  } else {
    if (t < 32) {
      float zs = 0.f;
#pragma unroll 8
      for (int ch = 0; ch < NCH; ++ch)
        zs += zpart[(size_t)ch * 2048 + (s * 2 + oo) * 32 + t];
      rzs[t] = 1.f / zs;
    }
  }
  __syncthreads();
  const float sv = acc * rzs[l31];
  sqs[t] = sv * sv;
  __syncthreads();
  float sq = 0.f;
#pragma unroll
  for (int k = 0; k < 16; ++k) sq += sqs[l31 + k * 32];
  const float f = (sq / (1.f + sq)) * rsqrtf(sq + 1e-9f);
  const float v = sv * f;

  if constexpr (PASS == 0)      vss[tid] = v;
  else if constexpr (PASS == 1) vss[tid] += v;
  else {
    const int b = (s & 1) * 32 + l31;
    const int o = (s >> 1) * 2 + oo;
    const int d = (rr & 3) + 8 * (rr >> 2) + 4 * hb;
    out[(b * 32 + o) * 16 + d] = v;
  }
}

// ---------------------------------------------------------------------------
// fp32 fallback path (R8 kernel + old reducers), for small ws only.
// ---------------------------------------------------------------------------
template<bool WEIGHTED, int NCH>
__global__ __launch_bounds__(512) void fusedF32(
    const float* __restrict__ x, const float* __restrict__ W,
    const float* __restrict__ vs, float* __restrict__ part,
    float* __restrict__ zpart)
{
  constexpr int CI  = IC / NCH;
  constexpr int NSW = CI / 8;
  const int t    = threadIdx.x;
  const int xcd  = blockIdx.x & 7;
  const int q    = blockIdx.x >> 3;
  const int ch   = (q >> 2) * 8 + xcd;
  const int bh   = q & 3;
  const int lane = t & 63;
  const int wv   = t >> 6;
  const int og   = wv >> 2;
  const int bset = wv & 3;
  const int op   = lane >> 2;
  const int dq   = lane & 3;
  const int o    = og * 16 + op;
  const int rot  = lane & 7;
  const int i0   = ch * CI;
  const int jb   = o * 32 + dq * 8;
  const int bl0  = bset * 4;
  const int b0   = bh * 16 + bl0;

  __shared__ float Wbuf[2][4096];
  __shared__ float xall[1024];

  const float4* Wg = (const float4*)W;
  const float4* xg = (const float4*)x;

  float4 acc[4];
  float  zacc[4];
  float4 vreg[4];
#pragma unroll
  for (int k = 0; k < 4; ++k) { acc[k] = make_float4(0,0,0,0); zacc[k] = 0.f; }

  if constexpr (WEIGHTED) {
#pragma unroll
    for (int bb = 0; bb < 4; ++bb)
      vreg[bb] = *(const float4*)(vs + ((size_t)(b0 + bb) * 32 + o) * 16 + dq * 4);
  }

  auto stageW = [&](int i, int nb) {
    const float4* Wi = Wg + (size_t)i * 1024;
#pragma unroll
    for (int k = 0; k < 2; ++k) {
      const int p   = wv * 128 + k * 64 + lane;
      const int src = (p & ~7) | ((p & 7) ^ ((p >> 3) & 7));
      GLOAD_LDS16(Wi + src, &Wbuf[nb][(wv * 128 + k * 64) * 4]);
    }
  };
  auto stageX = [&](int sw) {
    if (t < 256) {
      const int b = t >> 4, r = t & 15;
      const int ia = i0 + sw * 8 + (r >> 1);
      GLOAD_LDS16(xg + ((size_t)(bh * 16 + b) * IC + ia) * 2 + (r & 1),
                  &xall[(wv * 64) * 4]);
    }
  };

  stageX(0);
  stageW(i0, 0);
  int cur = 0;

#pragma unroll 1
  for (int sw = 0; sw < NSW; ++sw) {
#pragma unroll 1
    for (int j = 0; j < 8; ++j) {
      const int ii = sw * 8 + j;
      __syncthreads();
      if (ii + 1 < CI) stageW(i0 + ii + 1, cur ^ 1);

      const float* Wb = &Wbuf[cur][0];
      float4 wr[8];
#pragma unroll
      for (int r = 0; r < 8; ++r)
        wr[r] = *(const float4*)&Wb[(jb + (r ^ rot)) * 4];

#pragma unroll
      for (int bb = 0; bb < 4; ++bb) {
        const int bl = bl0 + bb;
        const float4 xa = *(const float4*)&xall[bl * 64 + j * 8];
        const float4 xc = *(const float4*)&xall[bl * 64 + j * 8 + 4];
        float4 u;
        u.x = dot8(wr[0], wr[1], xa, xc);
        u.y = dot8(wr[2], wr[3], xa, xc);
        u.z = dot8(wr[4], wr[5], xa, xc);
        u.w = dot8(wr[6], wr[7], xa, xc);
        if constexpr (!WEIGHTED) {
          acc[bb].x += u.x; acc[bb].y += u.y; acc[bb].z += u.z; acc[bb].w += u.w;
        } else {
          const float4 vv = vreg[bb];
          float pd = u.x * vv.x + u.y * vv.y + u.z * vv.z + u.w * vv.w;
          pd += __shfl_xor(pd, 1);
          pd += __shfl_xor(pd, 2);
          const float p = __expf(pd);
          acc[bb].x = fmaf(p, u.x, acc[bb].x);
          acc[bb].y = fmaf(p, u.y, acc[bb].y);
          acc[bb].z = fmaf(p, u.z, acc[bb].z);
          acc[bb].w = fmaf(p, u.w, acc[bb].w);
          zacc[bb] += p;
        }
      }
      cur ^= 1;
    }
    if (sw + 1 < NSW) { __syncthreads(); stageX(sw + 1); }
  }

  float4* part4 = (float4*)part;
#pragma unroll
  for (int bb = 0; bb < 4; ++bb) {
    const int b = b0 + bb;
    part4[((size_t)ch * 64 + b) * 128 + o * 4 + dq] = acc[bb];
    if constexpr (WEIGHTED) {
      if (dq == 0) zpart[(size_t)ch * 2048 + b * 32 + o] = zacc[bb];
    }
  }
}

template<int PASS, int NCH>
__global__ __launch_bounds__(256) void reduceSquash(
    const float* __restrict__ part, const float* __restrict__ rz,
    float* __restrict__ vsio, float* __restrict__ out)
{
  const int g = blockIdx.x * 256 + threadIdx.x;
  float s = 0.f;
#pragma unroll 8
  for (int ch = 0; ch < NCH; ++ch) s += part[(size_t)ch * 32768 + g];
  if constexpr (PASS == 0) s *= (1.f / 2048.f);
  else                     s *= rz[g >> 4];

  float sq = s * s;
#pragma unroll
  for (int k = 1; k < 16; k <<= 1) sq += __shfl_xor(sq, k);
  const float f = (sq / (1.f + sq)) * rsqrtf(sq + 1e-9f);
  const float v = s * f;

  if constexpr (PASS == 0)      vsio[g] = v;
  else if constexpr (PASS == 1) vsio[g] += v;
  else                          out[g] = v;
}

template<int NCH>
__global__ __launch_bounds__(256) void zredK(
    const float* __restrict__ zpart, float* __restrict__ rz)
{
  const int j = blockIdx.x * 256 + threadIdx.x;
  float zs = 0.f;
#pragma unroll 8
  for (int ch = 0; ch < NCH; ++ch) zs += zpart[(size_t)ch * 2048 + j];
  rz[j] = 1.f / zs;
}

// ---------------------------------------------------------------------------
extern "C" void kernel_launch(void* const* d_in, const int* in_sizes, int n_in,
                              void* d_out, int out_size, void* d_ws, size_t ws_size,
                              hipStream_t stream) {
  (void)in_sizes; (void)n_in; (void)out_size;
  const float* x = (const float*)d_in[0];
  const float* W = (const float*)d_in[1];
  float* out = (float*)d_out;
  float* ws  = (float*)d_ws;

  const size_t WBF_US = (size_t)IC * 8192;
  const size_t XB_US  = (size_t)IC * 1024;

  auto runM = [&](auto tag) {
    constexpr int NCH = decltype(tag)::value;
    float* part  = ws;                                  // [NCH][32768] scrambled
    float* zpart = part + (size_t)NCH * 32768;          // [NCH][2048] scrambled
    float* vsb   = zpart + (size_t)NCH * 2048;          // [32768] scrambled vs
    unsigned short* Wbf = (unsigned short*)(vsb + 32768);
    unsigned short* xbp = Wbf + WBF_US;

    const dim3 b256(256), b512(512), gF(8 * NCH), gR(64);
    convW<<<dim3(8192), b256, 0, stream>>>(W, Wbf);
    convX<<<dim3(1024), b256, 0, stream>>>(x, xbp);
    // pass 1: uniform c -> v1
    fusedM<false, NCH><<<gF, b256, 0, stream>>>(Wbf, xbp, nullptr, part, nullptr);
    rsqM<0, NCH><<<gR, b512, 0, stream>>>(part, nullptr, vsb, nullptr);
    // pass 2: p = exp(u.v1) -> v2; vs = v1+v2
    fusedM<true, NCH><<<gF, b256, 0, stream>>>(Wbf, xbp, vsb, part, zpart);
    rsqM<1, NCH><<<gR, b512, 0, stream>>>(part, zpart, vsb, nullptr);
    // pass 3: p = exp(u.(v1+v2)) -> v3 = out
    fusedM<true, NCH><<<gF, b256, 0, stream>>>(Wbf, xbp, vsb, part, zpart);
    rsqM<2, NCH><<<gR, b512, 0, stream>>>(part, zpart, nullptr, out);
  };

  auto runF = [&](auto tag) {
    constexpr int NCH = decltype(tag)::value;
    float* part  = ws;
    float* zpart = part + (size_t)NCH * 32768;
    float* rz    = zpart + (size_t)NCH * 2048;
    float* vsb   = rz + 2048;

    const dim3 gF(4 * NCH), bF(512), b256(256), gR(128);
    fusedF32<false, NCH><<<gF, bF, 0, stream>>>(x, W, nullptr, part, nullptr);
    reduceSquash<0, NCH><<<gR, b256, 0, stream>>>(part, nullptr, vsb, nullptr);
    fusedF32<true, NCH><<<gF, bF, 0, stream>>>(x, W, vsb, part, zpart);
    zredK<NCH><<<dim3(8), b256, 0, stream>>>(zpart, rz);
    reduceSquash<1, NCH><<<gR, b256, 0, stream>>>(part, rz, vsb, nullptr);
    fusedF32<true, NCH><<<gF, bF, 0, stream>>>(x, W, vsb, part, zpart);
    zredK<NCH><<<dim3(8), b256, 0, stream>>>(zpart, rz);
    reduceSquash<2, NCH><<<gR, b256, 0, stream>>>(part, rz, nullptr, out);
  };

  auto needM = [&](size_t nch) -> size_t {
    return (nch * 32768 + nch * 2048 + 32768) * 4 + (WBF_US + XB_US) * 2;
  };
  const size_t needF256 = ((size_t)256 * 32768 + 256ul * 2048 + 2048 + 32768) * 4;

  if      (ws_size >= needM(256)) runM(std::integral_constant<int, 256>{});
  else if (ws_size >= needM(128)) runM(std::integral_constant<int, 128>{});
  else if (ws_size >= needM(64))  runM(std::integral_constant<int, 64>{});
  else if (ws_size >= needF256)   runF(std::integral_constant<int, 256>{});
  else                            runF(std::integral_constant<int, 64>{});
}

// Round 20
// 95.345 us; speedup vs baseline: 1.3595x; 1.3595x over previous
//
#include <hip/hip_runtime.h>
#include <math.h>

#define B_ 64
#define IC 2048
#define OC 32
#define OD 16
#define ID 8

typedef __attribute__((ext_vector_type(8)))  short s16x8;
typedef __attribute__((ext_vector_type(16))) float f32x16;

#define GLOAD_LDS16(gp, lp)                                                       \
  __builtin_amdgcn_global_load_lds((const __attribute__((address_space(1))) void*)(gp), \
                                   (__attribute__((address_space(3))) void*)(lp), \
                                   16, 0, 0)

__device__ __forceinline__ unsigned short f2bf(float f) {      // RNE f32->bf16
  unsigned u = __float_as_uint(f);
  return (unsigned short)((u + 0x7fffu + ((u >> 16) & 1u)) >> 16);
}
__device__ __forceinline__ float bf2f(unsigned short h) {
  return __uint_as_float(((unsigned)h) << 16);
}
__device__ __forceinline__ f32x16 mfma16(s16x8 a, s16x8 b, f32x16 c) {
  return __builtin_amdgcn_mfma_f32_32x32x16_bf16(a, b, c, 0, 0, 0);
}
__device__ __forceinline__ float dot8(const float4 w0, const float4 w1,
                                      const float4 xa, const float4 xb) {
  return w0.x*xa.x + w0.y*xa.y + w0.z*xa.z + w0.w*xa.w
       + w1.x*xb.x + w1.y*xb.y + w1.z*xb.z + w1.w*xb.w;
}

// ---------------------------------------------------------------------------
// One-time split-bf16 conversion, W and x merged into ONE launch (R20):
// blocks [0,8192) convert W (2,097,152 f4), blocks [8192,9216) convert x.
// Bodies are byte-identical to the proven R14-R16 convW/convX kernels.
// Wbf: [i][half][o][d][m] ushort; xb: [i][half][b][m] ushort.
// ---------------------------------------------------------------------------
__global__ __launch_bounds__(256) void convWX(
    const float* __restrict__ W, const float* __restrict__ x,
    unsigned short* __restrict__ Wbf, unsigned short* __restrict__ xb)
{
  const int bid = blockIdx.x;
  if (bid < 8192) {
    const int e4 = bid * 256 + threadIdx.x;
    const float4 v = ((const float4*)W)[e4];
    const int i = e4 >> 10;
    const int r = (e4 & 1023) << 2;
    ushort4 h, l;
    h.x = f2bf(v.x); l.x = f2bf(v.x - bf2f(h.x));
    h.y = f2bf(v.y); l.y = f2bf(v.y - bf2f(h.y));
    h.z = f2bf(v.z); l.z = f2bf(v.z - bf2f(h.z));
    h.w = f2bf(v.w); l.w = f2bf(v.w - bf2f(h.w));
    *(ushort4*)&Wbf[(size_t)i * 8192 + r]        = h;
    *(ushort4*)&Wbf[(size_t)i * 8192 + 4096 + r] = l;
  } else {
    const int idx = (bid - 8192) * 256 + threadIdx.x;
    const int m2 = idx & 1, i = (idx >> 1) & 2047, b = idx >> 12;
    const float4 v = *(const float4*)(x + (size_t)b * 16384 + i * 8 + m2 * 4);
    ushort4 h, l;
    h.x = f2bf(v.x); l.x = f2bf(v.x - bf2f(h.x));
    h.y = f2bf(v.y); l.y = f2bf(v.y - bf2f(h.y));
    h.z = f2bf(v.z); l.z = f2bf(v.z - bf2f(h.z));
    h.w = f2bf(v.w); l.w = f2bf(v.w - bf2f(h.w));
    *(ushort4*)&xb[(size_t)i * 1024 + b * 8 + m2 * 4]       = h;
    *(ushort4*)&xb[(size_t)i * 1024 + 512 + b * 8 + m2 * 4] = l;
  }
}

// ---------------------------------------------------------------------------
// MFMA routing pass (R16, proven): no LDS, no barriers; vs in scrambled
// layout (coalesced 256B loads); depth-2 prefetch via 3 rotating register
// stages (all indices compile-time under full unroll).
// grid = 8*NCH, bid = q*NCH + ch (NCH%8==0 -> same-ch blocks on one XCD).
// wave slot s = q*4+wv: opair = s>>1, bt = s&1; one 32x32 tile per wave.
// part/zpart stored in MFMA-register ("scrambled") order: coalesced stores.
// ---------------------------------------------------------------------------
template<bool WEIGHTED, int NCH>
__global__ __launch_bounds__(256) void fusedM(
    const unsigned short* __restrict__ Wbf, const unsigned short* __restrict__ xb,
    const float* __restrict__ vss, float* __restrict__ part,
    float* __restrict__ zpart)
{
  constexpr int CI = IC / NCH;
  const int t     = threadIdx.x;
  const int ch    = blockIdx.x % NCH;
  const int q     = blockIdx.x / NCH;
  const int lane  = t & 63;
  const int wv    = t >> 6;
  const int s     = q * 4 + wv;          // 0..31
  const int opair = s >> 1;
  const int bt    = s & 1;
  const int l31   = lane & 31;
  const int hb    = lane >> 5;
  const int i0    = ch * CI;

  const unsigned short* ap =
      Wbf + (size_t)i0 * 8192 + opair * 256 + (l31 >> 4) * 128 + (lane & 15) * 8;
  const unsigned short* bp =
      xb + (size_t)i0 * 1024 + hb * 512 + bt * 256 + l31 * 8;

  f32x16 acc = (f32x16)0.0f;
  float zA = 0.f, zB = 0.f;
  float vsr[16];

  if constexpr (WEIGHTED) {
    const float* vp = vss + s * 1024 + hb * 32 + l31;   // coalesced 256B/ld
#pragma unroll
    for (int r = 0; r < 16; ++r) vsr[r] = vp[r * 64];
  }

  s16x8 AH[3], AL[3], BV[3];
  AH[0] = *(const s16x8*)ap;
  AL[0] = *(const s16x8*)(ap + 4096);
  BV[0] = *(const s16x8*)bp;
  if (CI > 1) {
    AH[1] = *(const s16x8*)(ap + 8192);
    AL[1] = *(const s16x8*)(ap + 8192 + 4096);
    BV[1] = *(const s16x8*)(bp + 1024);
  }

#pragma unroll
  for (int ii = 0; ii < CI; ++ii) {
    const int cs = ii % 3;
    const int ns = (ii + 2) % 3;
    if (ii + 2 < CI) {                       // issue 2 iters ahead
      AH[ns] = *(const s16x8*)(ap + (size_t)(ii + 2) * 8192);
      AL[ns] = *(const s16x8*)(ap + (size_t)(ii + 2) * 8192 + 4096);
      BV[ns] = *(const s16x8*)(bp + (size_t)(ii + 2) * 1024);
    }

    if constexpr (!WEIGHTED) {
      acc = mfma16(AH[cs], BV[cs], acc);
      acc = mfma16(AL[cs], BV[cs], acc);
    } else {
      f32x16 u = mfma16(AH[cs], BV[cs], (f32x16)0.0f);
      u = mfma16(AL[cs], BV[cs], u);
      float pdA = 0.f, pdB = 0.f;
#pragma unroll
      for (int r = 0; r < 8; ++r)  pdA = fmaf(u[r], vsr[r], pdA);
#pragma unroll
      for (int r = 8; r < 16; ++r) pdB = fmaf(u[r], vsr[r], pdB);
      pdA += __shfl_xor(pdA, 32);            // add other hb's 8 d's
      pdB += __shfl_xor(pdB, 32);
      const float pA = __expf(pdA), pB = __expf(pdB);
#pragma unroll
      for (int r = 0; r < 8; ++r)  acc[r] = fmaf(pA, u[r], acc[r]);
#pragma unroll
      for (int r = 8; r < 16; ++r) acc[r] = fmaf(pB, u[r], acc[r]);
      zA += pA; zB += pB;
    }
  }

  // scrambled, coalesced epilogue
  float* op = part + (size_t)ch * 32768;
#pragma unroll
  for (int r = 0; r < 16; ++r)
    op[(s * 16 + r) * 64 + hb * 32 + l31] = acc[r];
  if constexpr (WEIGHTED) {
    if (lane < 32) {
      zpart[(size_t)ch * 2048 + (s * 2 + 0) * 32 + lane] = zA;
      zpart[(size_t)ch * 2048 + (s * 2 + 1) * 32 + lane] = zB;
    }
  }
}

// ---------------------------------------------------------------------------
// Reduce+squash over scrambled part; vss kept scrambled (coalesced both
// directions); PASS 2 writes standard-layout out. grid 64 x 512.
// ---------------------------------------------------------------------------
template<int PASS, int NCH>
__global__ __launch_bounds__(512) void rsqM(
    const float* __restrict__ part, const float* __restrict__ zpart,
    float* __restrict__ vss, float* __restrict__ out)
{
  __shared__ float rzs[32];
  __shared__ float sqs[512];
  const int t   = threadIdx.x;
  const int blk = blockIdx.x;
  const int s   = blk >> 1, oo = blk & 1;
  const int l31 = t & 31, hb = (t >> 5) & 1, rr = t >> 6;
  const size_t tid = (size_t)blk * 512 + t;

  float acc = 0.f;
#pragma unroll 8
  for (int ch = 0; ch < NCH; ++ch) acc += part[(size_t)ch * 32768 + tid];

  if constexpr (PASS == 0) {
    if (t < 32) rzs[t] = 1.f / 2048.f;
  } else {
    if (t < 32) {
      float zs = 0.f;
#pragma unroll 8
      for (int ch = 0; ch < NCH; ++ch)
        zs += zpart[(size_t)ch * 2048 + (s * 2 + oo) * 32 + t];
      rzs[t] = 1.f / zs;
    }
  }
  __syncthreads();
  const float sv = acc * rzs[l31];
  sqs[t] = sv * sv;
  __syncthreads();
  float sq = 0.f;
#pragma unroll
  for (int k = 0; k < 16; ++k) sq += sqs[l31 + k * 32];
  const float f = (sq / (1.f + sq)) * rsqrtf(sq + 1e-9f);
  const float v = sv * f;

  if constexpr (PASS == 0)      vss[tid] = v;
  else if constexpr (PASS == 1) vss[tid] += v;
  else {
    const int b = (s & 1) * 32 + l31;
    const int o = (s >> 1) * 2 + oo;
    const int d = (rr & 3) + 8 * (rr >> 2) + 4 * hb;
    out[(b * 32 + o) * 16 + d] = v;
  }
}

// ---------------------------------------------------------------------------
// fp32 fallback path (R8 kernel + old reducers), for small ws only.
// ---------------------------------------------------------------------------
template<bool WEIGHTED, int NCH>
__global__ __launch_bounds__(512) void fusedF32(
    const float* __restrict__ x, const float* __restrict__ W,
    const float* __restrict__ vs, float* __restrict__ part,
    float* __restrict__ zpart)
{
  constexpr int CI  = IC / NCH;
  constexpr int NSW = CI / 8;
  const int t    = threadIdx.x;
  const int xcd  = blockIdx.x & 7;
  const int q    = blockIdx.x >> 3;
  const int ch   = (q >> 2) * 8 + xcd;
  const int bh   = q & 3;
  const int lane = t & 63;
  const int wv   = t >> 6;
  const int og   = wv >> 2;
  const int bset = wv & 3;
  const int op   = lane >> 2;
  const int dq   = lane & 3;
  const int o    = og * 16 + op;
  const int rot  = lane & 7;
  const int i0   = ch * CI;
  const int jb   = o * 32 + dq * 8;
  const int bl0  = bset * 4;
  const int b0   = bh * 16 + bl0;

  __shared__ float Wbuf[2][4096];
  __shared__ float xall[1024];

  const float4* Wg = (const float4*)W;
  const float4* xg = (const float4*)x;

  float4 acc[4];
  float  zacc[4];
  float4 vreg[4];
#pragma unroll
  for (int k = 0; k < 4; ++k) { acc[k] = make_float4(0,0,0,0); zacc[k] = 0.f; }

  if constexpr (WEIGHTED) {
#pragma unroll
    for (int bb = 0; bb < 4; ++bb)
      vreg[bb] = *(const float4*)(vs + ((size_t)(b0 + bb) * 32 + o) * 16 + dq * 4);
  }

  auto stageW = [&](int i, int nb) {
    const float4* Wi = Wg + (size_t)i * 1024;
#pragma unroll
    for (int k = 0; k < 2; ++k) {
      const int p   = wv * 128 + k * 64 + lane;
      const int src = (p & ~7) | ((p & 7) ^ ((p >> 3) & 7));
      GLOAD_LDS16(Wi + src, &Wbuf[nb][(wv * 128 + k * 64) * 4]);
    }
  };
  auto stageX = [&](int sw) {
    if (t < 256) {
      const int b = t >> 4, r = t & 15;
      const int ia = i0 + sw * 8 + (r >> 1);
      GLOAD_LDS16(xg + ((size_t)(bh * 16 + b) * IC + ia) * 2 + (r & 1),
                  &xall[(wv * 64) * 4]);
    }
  };

  stageX(0);
  stageW(i0, 0);
  int cur = 0;

#pragma unroll 1
  for (int sw = 0; sw < NSW; ++sw) {
#pragma unroll 1
    for (int j = 0; j < 8; ++j) {
      const int ii = sw * 8 + j;
      __syncthreads();
      if (ii + 1 < CI) stageW(i0 + ii + 1, cur ^ 1);

      const float* Wb = &Wbuf[cur][0];
      float4 wr[8];
#pragma unroll
      for (int r = 0; r < 8; ++r)
        wr[r] = *(const float4*)&Wb[(jb + (r ^ rot)) * 4];

#pragma unroll
      for (int bb = 0; bb < 4; ++bb) {
        const int bl = bl0 + bb;
        const float4 xa = *(const float4*)&xall[bl * 64 + j * 8];
        const float4 xc = *(const float4*)&xall[bl * 64 + j * 8 + 4];
        float4 u;
        u.x = dot8(wr[0], wr[1], xa, xc);
        u.y = dot8(wr[2], wr[3], xa, xc);
        u.z = dot8(wr[4], wr[5], xa, xc);
        u.w = dot8(wr[6], wr[7], xa, xc);
        if constexpr (!WEIGHTED) {
          acc[bb].x += u.x; acc[bb].y += u.y; acc[bb].z += u.z; acc[bb].w += u.w;
        } else {
          const float4 vv = vreg[bb];
          float pd = u.x * vv.x + u.y * vv.y + u.z * vv.z + u.w * vv.w;
          pd += __shfl_xor(pd, 1);
          pd += __shfl_xor(pd, 2);
          const float p = __expf(pd);
          acc[bb].x = fmaf(p, u.x, acc[bb].x);
          acc[bb].y = fmaf(p, u.y, acc[bb].y);
          acc[bb].z = fmaf(p, u.z, acc[bb].z);
          acc[bb].w = fmaf(p, u.w, acc[bb].w);
          zacc[bb] += p;
        }
      }
      cur ^= 1;
    }
    if (sw + 1 < NSW) { __syncthreads(); stageX(sw + 1); }
  }

  float4* part4 = (float4*)part;
#pragma unroll
  for (int bb = 0; bb < 4; ++bb) {
    const int b = b0 + bb;
    part4[((size_t)ch * 64 + b) * 128 + o * 4 + dq] = acc[bb];
    if constexpr (WEIGHTED) {
      if (dq == 0) zpart[(size_t)ch * 2048 + b * 32 + o] = zacc[bb];
    }
  }
}

template<int PASS, int NCH>
__global__ __launch_bounds__(256) void reduceSquash(
    const float* __restrict__ part, const float* __restrict__ rz,
    float* __restrict__ vsio, float* __restrict__ out)
{
  const int g = blockIdx.x * 256 + threadIdx.x;
  float s = 0.f;
#pragma unroll 8
  for (int ch = 0; ch < NCH; ++ch) s += part[(size_t)ch * 32768 + g];
  if constexpr (PASS == 0) s *= (1.f / 2048.f);
  else                     s *= rz[g >> 4];

  float sq = s * s;
#pragma unroll
  for (int k = 1; k < 16; k <<= 1) sq += __shfl_xor(sq, k);
  const float f = (sq / (1.f + sq)) * rsqrtf(sq + 1e-9f);
  const float v = s * f;

  if constexpr (PASS == 0)      vsio[g] = v;
  else if constexpr (PASS == 1) vsio[g] += v;
  else                          out[g] = v;
}

template<int NCH>
__global__ __launch_bounds__(256) void zredK(
    const float* __restrict__ zpart, float* __restrict__ rz)
{
  const int j = blockIdx.x * 256 + threadIdx.x;
  float zs = 0.f;
#pragma unroll 8
  for (int ch = 0; ch < NCH; ++ch) zs += zpart[(size_t)ch * 2048 + j];
  rz[j] = 1.f / zs;
}

// ---------------------------------------------------------------------------
extern "C" void kernel_launch(void* const* d_in, const int* in_sizes, int n_in,
                              void* d_out, int out_size, void* d_ws, size_t ws_size,
                              hipStream_t stream) {
  (void)in_sizes; (void)n_in; (void)out_size;
  const float* x = (const float*)d_in[0];
  const float* W = (const float*)d_in[1];
  float* out = (float*)d_out;
  float* ws  = (float*)d_ws;

  const size_t WBF_US = (size_t)IC * 8192;
  const size_t XB_US  = (size_t)IC * 1024;

  auto runM = [&](auto tag) {
    constexpr int NCH = decltype(tag)::value;
    float* part  = ws;                                  // [NCH][32768] scrambled
    float* zpart = part + (size_t)NCH * 32768;          // [NCH][2048] scrambled
    float* vsb   = zpart + (size_t)NCH * 2048;          // [32768] scrambled vs
    unsigned short* Wbf = (unsigned short*)(vsb + 32768);
    unsigned short* xbp = Wbf + WBF_US;

    const dim3 b256(256), b512(512), gF(8 * NCH), gR(64);
    // conversions (merged single launch)
    convWX<<<dim3(9216), b256, 0, stream>>>(W, x, Wbf, xbp);
    // pass 1: uniform c -> v1
    fusedM<false, NCH><<<gF, b256, 0, stream>>>(Wbf, xbp, nullptr, part, nullptr);
    rsqM<0, NCH><<<gR, b512, 0, stream>>>(part, nullptr, vsb, nullptr);
    // pass 2: p = exp(u.v1) -> v2; vs = v1+v2
    fusedM<true, NCH><<<gF, b256, 0, stream>>>(Wbf, xbp, vsb, part, zpart);
    rsqM<1, NCH><<<gR, b512, 0, stream>>>(part, zpart, vsb, nullptr);
    // pass 3: p = exp(u.(v1+v2)) -> v3 = out
    fusedM<true, NCH><<<gF, b256, 0, stream>>>(Wbf, xbp, vsb, part, zpart);
    rsqM<2, NCH><<<gR, b512, 0, stream>>>(part, zpart, nullptr, out);
  };

  auto runF = [&](auto tag) {
    constexpr int NCH = decltype(tag)::value;
    float* part  = ws;
    float* zpart = part + (size_t)NCH * 32768;
    float* rz    = zpart + (size_t)NCH * 2048;
    float* vsb   = rz + 2048;

    const dim3 gF(4 * NCH), bF(512), b256(256), gR(128);
    fusedF32<false, NCH><<<gF, bF, 0, stream>>>(x, W, nullptr, part, nullptr);
    reduceSquash<0, NCH><<<gR, b256, 0, stream>>>(part, nullptr, vsb, nullptr);
    fusedF32<true, NCH><<<gF, bF, 0, stream>>>(x, W, vsb, part, zpart);
    zredK<NCH><<<dim3(8), b256, 0, stream>>>(zpart, rz);
    reduceSquash<1, NCH><<<gR, b256, 0, stream>>>(part, rz, vsb, nullptr);
    fusedF32<true, NCH><<<gF, bF, 0, stream>>>(x, W, vsb, part, zpart);
    zredK<NCH><<<dim3(8), b256, 0, stream>>>(zpart, rz);
    reduceSquash<2, NCH><<<gR, b256, 0, stream>>>(part, rz, nullptr, out);
  };

  auto needM = [&](size_t nch) -> size_t {
    return (nch * 32768 + nch * 2048 + 32768) * 4 + (WBF_US + XB_US) * 2;
  };
  const size_t needF256 = ((size_t)256 * 32768 + 256ul * 2048 + 2048 + 32768) * 4;

  if      (ws_size >= needM(128)) runM(std::integral_constant<int, 128>{});
  else if (ws_size >= needM(64))  runM(std::integral_constant<int, 64>{});
  else if (ws_size >= needF256)   runF(std::integral_constant<int, 256>{});
  else                            runF(std::integral_constant<int, 64>{});
}